// Round 10
// baseline (133.067 us; speedup 1.0000x reference)
//
#include <hip/hip_runtime.h>

#define EPS 1e-5f
#define TEMP 50.0f
#define CCH 64
#define HH 128
#define WW 128
#define HWSZ (HH * WW)
#define CEPS2 (CCH * EPS * EPS)

#define ITW 8           // interior tile: 8 wide
#define ITH 4           // x 4 high = 32 px/block
#define HTW 12          // halo: 12 wide
#define HTH 8           //       8 high
#define HPX (HTW * HTH) // 96 halo pixels
#define HPAD 97         // HPAD%4==1: quarter-plane stride 2*HPAD*4 words == 8
                        // mod 32 -> 8-lane group (2px x 4 quarters) covers all
                        // 32 banks: conflict-free b128 reads

typedef _Float16 h16;
typedef h16 h2v __attribute__((ext_vector_type(2)));
typedef h16 h8v __attribute__((ext_vector_type(8)));
union H8 { h8v v; h2v p[4]; };

__device__ __forceinline__ float fdot2(h2v a, h2v b, float c) {
#if __has_builtin(__builtin_amdgcn_fdot2)
    return __builtin_amdgcn_fdot2(a, b, c, false);   // v_dot2_f32_f16
#else
    return c + (float)a[0] * (float)b[0] + (float)a[1] * (float)b[1];
#endif
}

// Quad-lane butterfly sum via DPP quad_perm (VALU pipe, no LDS traffic).
__device__ __forceinline__ float quad_sum(float x) {
#if __has_builtin(__builtin_amdgcn_mov_dpp)
    int i = __builtin_bit_cast(int, x);
    int a = __builtin_amdgcn_mov_dpp(i, 0xB1, 0xF, 0xF, true);  // xor 1
    float x1 = x + __builtin_bit_cast(float, a);
    int j = __builtin_bit_cast(int, x1);
    int b = __builtin_amdgcn_mov_dpp(j, 0x4E, 0xF, 0xF, true);  // xor 2
    return x1 + __builtin_bit_cast(float, b);
#else
    float x1 = x + __shfl_xor(x, 1);
    return x1 + __shfl_xor(x1, 2);
#endif
}

// SINGLE kernel: per-block in-LDS transpose staging from native [C][H][W],
// then one-pass online accumulation (center logit == softmax max exactly,
// by Cauchy-Schwarz, so weights are final on first visit).
// Block: 128 threads = 2 waves, 8x4 interior tile.
// Staging map: c = t&63 (one channel/thread), rows (t>>6)+{0,2,4,6},
// 6 predicated float2 loads per row (w offsets even -> 8B-aligned, exact
// edge predication), transposed h16-pair writes into tile (2-way shared
// dwords across lanes -> conflict-free per m136).
__global__ __launch_bounds__(128, 4) void rv_one(const float* __restrict__ x,
                                                 float* __restrict__ out) {
    __shared__ h8v  tile[8][HPAD];   // 12416 B
    __shared__ float sh_q[HPX];      // 384 B

    const int t  = threadIdx.x;
    const int w0 = blockIdx.x * ITW;
    const int h0 = blockIdx.y * ITH;
    const int b  = blockIdx.z;
    const float* xb = x + (size_t)b * (CCH * HWSZ);

    // ---- Stage + transpose: 64 ch x 8 rows x 12 w, zero-padded ----
    const int c   = t & 63;
    const int q8  = c >> 3;          // h8v plane
    const int sub = c & 7;           // element within h8v
    const float* cp = xb + (size_t)c * HWSZ;
#pragma unroll
    for (int i = 0; i < 4; ++i) {
        const int row = (t >> 6) + 2 * i;         // 0..7
        const int gh = h0 + row - 2;
        const bool rowok = (unsigned)gh < (unsigned)HH;
        const float* rp = cp + gh * WW + (w0 - 2);
        h16* dst = (h16*)&tile[q8][row * HTW];
#pragma unroll
        for (int k = 0; k < 6; ++k) {
            const int gw = w0 - 2 + 2 * k;
            float2 v = make_float2(0.f, 0.f);
            if (rowok && (unsigned)gw < (unsigned)WW)
                v = *(const float2*)(rp + 2 * k);
            dst[(2 * k) * 8 + sub]     = (h16)v.x;
            dst[(2 * k + 1) * 8 + sub] = (h16)v.y;
        }
    }
    __syncthreads();

    // ---- Per-halo-pixel sumsq (from the SAME rounded f16 values) ----
    if (t < HPX) {
        float q = 0.f;
#pragma unroll
        for (int hq = 0; hq < 8; ++hq) {
            H8 u; u.v = tile[hq][t];
#pragma unroll
            for (int j = 0; j < 4; ++j) q = fdot2(u.p[j], u.p[j], q);
        }
        sh_q[t] = q;
    }
    __syncthreads();

    const int qg  = t & 3;               // channel quarter: planes 2qg, 2qg+1
    const int pix = t >> 2;              // 0..31
    const int r   = pix >> 3;            // 0..3
    const int cl  = pix & 7;             // 0..7
    const int cpx = (r + 2) * HTW + (cl + 2);

    const float rinvC = rsqrtf(sh_q[cpx] + CEPS2);

    H8 ctr0, ctr1;
    ctr0.v = tile[2 * qg][cpx];
    ctr1.v = tile[2 * qg + 1][cpx];

    h2v acc[8] = {};                     // unnormalized numerator, 16 ch
    float wsum = 0.f;

#pragma unroll
    for (int dr = 0; dr < 5; ++dr) {
#pragma unroll
        for (int dc = 0; dc < 5; ++dc) {
            const int npx = (r + dr) * HTW + (cl + dc);
            H8 a0, a1;
            a0.v = tile[2 * qg][npx];
            a1.v = tile[2 * qg + 1][npx];
            float d = 0.f;
#pragma unroll
            for (int j = 0; j < 4; ++j) d = fdot2(ctr0.p[j], a0.p[j], d);
#pragma unroll
            for (int j = 0; j < 4; ++j) d = fdot2(ctr1.p[j], a1.p[j], d);
            d = quad_sum(d);             // full 64-ch dot in all 4 quad lanes
            // weight relative to center: exp(TEMP*(sim-1)), sim<=1 exact max
            const float N2n = sh_q[npx] + CEPS2;
            const float sim = (d + CEPS2) * (rsqrtf(N2n) * rinvC);
            const float wn = __expf(fmaf(TEMP, sim, -TEMP));
            wsum += wn;
            const h16 wh = (h16)wn;
            const h2v w2 = {wh, wh};
#pragma unroll
            for (int j = 0; j < 4; ++j) {
                acc[j]     = a0.p[j] * w2 + acc[j];
                acc[4 + j] = a1.p[j] * w2 + acc[4 + j];
            }
        }
    }

    // ---- Normalize + store this quarter's 16 channels ----
    const float rs = 1.f / wsum;
    const size_t obase = (size_t)b * (CCH * HWSZ)
                       + (size_t)(qg * 16) * HWSZ
                       + (h0 + r) * WW + (w0 + cl);
#pragma unroll
    for (int j = 0; j < 8; ++j) {
        const float f0 = (float)acc[j][0];
        const float f1 = (float)acc[j][1];
        out[obase + (size_t)(2 * j) * HWSZ]     = fmaf(f0, rs, EPS);
        out[obase + (size_t)(2 * j + 1) * HWSZ] = fmaf(f1, rs, EPS);
    }
}

extern "C" void kernel_launch(void* const* d_in, const int* in_sizes, int n_in,
                              void* d_out, int out_size, void* d_ws, size_t ws_size,
                              hipStream_t stream) {
    const float* x = (const float*)d_in[0];
    float* outp = (float*)d_out;
    rv_one<<<dim3(WW / ITW, HH / ITH, 4), dim3(128, 1, 1), 0, stream>>>(x, outp);
}

// Round 11
// 87.507 us; speedup vs baseline: 1.5207x; 1.5207x over previous
//
#include <hip/hip_runtime.h>

#define EPS 1e-5f
#define TEMP 50.0f
#define CCH 64
#define HH 128
#define WW 128
#define HWSZ (HH * WW)
#define CEPS2 (CCH * EPS * EPS)

#define ITW 16          // interior tile: 16 wide (w0 % 16 == 0 -> body rows
                        // are whole aligned 64B lines)
#define ITH 4           // x 4 high = 64 px/block
#define HTW 20          // halo: 20 wide
#define HTH 8           //       8 high
#define HPX (HTW * HTH) // 160 halo pixels; plane stride 160*16B = 640 words
                        // == 0 mod 32 -> even/odd lane pairs 2-way (free)

typedef _Float16 h16;
typedef h16 h2v __attribute__((ext_vector_type(2)));
typedef h16 h8v __attribute__((ext_vector_type(8)));
union H8 { h8v v; h2v p[4]; };

__device__ __forceinline__ float fdot2(h2v a, h2v b, float c) {
#if __has_builtin(__builtin_amdgcn_fdot2)
    return __builtin_amdgcn_fdot2(a, b, c, false);   // v_dot2_f32_f16
#else
    return c + (float)a[0] * (float)b[0] + (float)a[1] * (float)b[1];
#endif
}

// Lane-pair butterfly (xor 1) via DPP quad_perm: VALU pipe, no LDS traffic.
__device__ __forceinline__ float pair_sum(float x) {
#if __has_builtin(__builtin_amdgcn_mov_dpp)
    int i = __builtin_bit_cast(int, x);
    int a = __builtin_amdgcn_mov_dpp(i, 0xB1, 0xF, 0xF, true);  // quad xor 1
    return x + __builtin_bit_cast(float, a);
#else
    return x + __shfl_xor(x, 1);
#endif
}

// SINGLE kernel. Block: 128 threads = 2 waves, 16x4 interior tile.
// Staging from native [C][H][W]:
//   body: 512 (c,row) segments x 16 floats = aligned 64B lines, float4 x4 lanes
//   edges: 2 floats each side, from neighbor blocks' body lines (L2-hot)
// Compute: one-pass online accumulation; center logit == softmax max exactly
// (Cauchy-Schwarz), so each neighbor's weight is final on first visit.
// thread t -> pixel (t>>1), channel-half (t&1, 32 ch = planes 4*half..4*half+3).
__global__ __launch_bounds__(128, 2) void rv_one(const float* __restrict__ x,
                                                 float* __restrict__ out) {
    __shared__ h8v  tile[8][HPX];    // 20480 B
    __shared__ float sh_q[HPX];      // 640 B

    const int t  = threadIdx.x;
    const int w0 = blockIdx.x * ITW;
    const int h0 = blockIdx.y * ITH;
    const int b  = blockIdx.z;
    const float* xb = x + (size_t)b * (CCH * HWSZ);

    // ---- Body staging: k = it*128+t over 2048; q=k&3 (float4 lane),
    // seg=k>>2: c=seg>>3, row=seg&7. One wave-inst = 16 full 64B lines. ----
#pragma unroll
    for (int it = 0; it < 16; ++it) {
        const int k   = it * 128 + t;
        const int q   = k & 3;
        const int seg = k >> 2;
        const int c   = seg >> 3;
        const int row = seg & 7;
        const int gh  = h0 + row - 2;
        float4 v = make_float4(0.f, 0.f, 0.f, 0.f);
        if ((unsigned)gh < (unsigned)HH)
            v = *(const float4*)(xb + (size_t)c * HWSZ + gh * WW + w0 + 4 * q);
        h16* dst = (h16*)&tile[c >> 3][row * HTW + 2 + 4 * q];
        const int sub = c & 7;
        dst[0 * 8 + sub] = (h16)v.x;
        dst[1 * 8 + sub] = (h16)v.y;
        dst[2 * 8 + sub] = (h16)v.z;
        dst[3 * 8 + sub] = (h16)v.w;
    }
    // ---- Edge staging: k over 1024; side=k&1, seg=k>>1 ----
#pragma unroll
    for (int it = 0; it < 8; ++it) {
        const int k    = it * 128 + t;
        const int side = k & 1;
        const int seg  = k >> 1;
        const int c    = seg >> 3;
        const int row  = seg & 7;
        const int gh   = h0 + row - 2;
        const int gw   = side ? (w0 + 16) : (w0 - 2);
        float2 v = make_float2(0.f, 0.f);
        if ((unsigned)gh < (unsigned)HH && (unsigned)gw < (unsigned)(WW - 1))
            v = *(const float2*)(xb + (size_t)c * HWSZ + gh * WW + gw);
        h16* dst = (h16*)&tile[c >> 3][row * HTW + (side ? 18 : 0)];
        const int sub = c & 7;
        dst[0 * 8 + sub] = (h16)v.x;
        dst[1 * 8 + sub] = (h16)v.y;
    }
    __syncthreads();

    // ---- Per-halo-pixel sumsq (from the SAME rounded f16 values) ----
#pragma unroll
    for (int rep = 0; rep < 2; ++rep) {
        const int idx = rep * 128 + t;
        if (idx < HPX) {
            float q = 0.f;
#pragma unroll
            for (int hq = 0; hq < 8; ++hq) {
                H8 u; u.v = tile[hq][idx];
#pragma unroll
                for (int j = 0; j < 4; ++j) q = fdot2(u.p[j], u.p[j], q);
            }
            sh_q[idx] = q;
        }
    }
    __syncthreads();

    const int half = t & 1;              // planes 4*half .. 4*half+3
    const int pix  = t >> 1;             // 0..63
    const int r    = pix >> 4;           // 0..3
    const int cl   = pix & 15;           // 0..15
    const int cpx  = (r + 2) * HTW + (cl + 2);

    const float rinvC = rsqrtf(sh_q[cpx] + CEPS2);

    H8 ctr[4];
#pragma unroll
    for (int g = 0; g < 4; ++g) ctr[g].v = tile[4 * half + g][cpx];

    h2v acc[16] = {};                    // unnormalized numerator, 32 ch
    float wsum = 0.f;

#pragma unroll
    for (int dr = 0; dr < 5; ++dr) {
#pragma unroll
        for (int dc = 0; dc < 5; ++dc) {
            const int npx = (r + dr) * HTW + (cl + dc);
            H8 a[4];
#pragma unroll
            for (int g = 0; g < 4; ++g) a[g].v = tile[4 * half + g][npx];
            float d = 0.f;
#pragma unroll
            for (int g = 0; g < 4; ++g)
#pragma unroll
                for (int j = 0; j < 4; ++j) d = fdot2(ctr[g].p[j], a[g].p[j], d);
            d = pair_sum(d);             // full 64-ch dot in both pair lanes
            // weight vs center: exp(TEMP*(sim-1)); sim<=1, center==1 exactly
            const float N2n = sh_q[npx] + CEPS2;
            const float sim = (d + CEPS2) * (rsqrtf(N2n) * rinvC);
            const float wn = __expf(fmaf(TEMP, sim, -TEMP));
            wsum += wn;
            const h16 wh = (h16)wn;
            const h2v w2 = {wh, wh};
#pragma unroll
            for (int g = 0; g < 4; ++g)
#pragma unroll
                for (int j = 0; j < 4; ++j)
                    acc[g * 4 + j] = a[g].p[j] * w2 + acc[g * 4 + j];
        }
    }

    // ---- Normalize + store this half's 32 channels ----
    // Store inst j: wave = 2 planes x 2 rows x 16 w -> 4 full 64B lines.
    const float rs = 1.f / wsum;
    const size_t obase = (size_t)b * (CCH * HWSZ)
                       + (size_t)(half * 32) * HWSZ
                       + (h0 + r) * WW + (w0 + cl);
#pragma unroll
    for (int j = 0; j < 16; ++j) {
        const float f0 = (float)acc[j][0];
        const float f1 = (float)acc[j][1];
        out[obase + (size_t)(2 * j) * HWSZ]     = fmaf(f0, rs, EPS);
        out[obase + (size_t)(2 * j + 1) * HWSZ] = fmaf(f1, rs, EPS);
    }
}

extern "C" void kernel_launch(void* const* d_in, const int* in_sizes, int n_in,
                              void* d_out, int out_size, void* d_ws, size_t ws_size,
                              hipStream_t stream) {
    const float* x = (const float*)d_in[0];
    float* outp = (float*)d_out;
    rv_one<<<dim3(WW / ITW, HH / ITH, 4), dim3(128, 1, 1), 0, stream>>>(x, outp);
}

// Round 13
// 81.395 us; speedup vs baseline: 1.6348x; 1.0751x over previous
//
#include <hip/hip_runtime.h>

#define EPS 1e-5f
#define TEMP 50.0f
#define CCH 64
#define HH 128
#define WW 128
#define HWSZ (HH * WW)
#define CEPS2 (CCH * EPS * EPS)
#define K2E 72.13475204444817f   // TEMP / ln(2)

#define IT 8            // interior tile: 8x8 pixels
#define HT 12           // halo tile: 12x12
#define HPX (HT * HT)   // 144 halo pixels
#define HPAD 145        // HPAD%4==1: quarter-plane stride -> 8-lane group
                        // (2 px x 4 quarters) covers all 32 banks

typedef _Float16 h16;
typedef h16 h2v __attribute__((ext_vector_type(2)));
typedef h16 h8v __attribute__((ext_vector_type(8)));
union H8 { h8v v; h2v p[4]; };

__device__ __forceinline__ float fdot2(h2v a, h2v b, float c) {
#if __has_builtin(__builtin_amdgcn_fdot2)
    return __builtin_amdgcn_fdot2(a, b, c, false);   // v_dot2_f32_f16
#else
    return c + (float)a[0] * (float)b[0] + (float)a[1] * (float)b[1];
#endif
}

__device__ __forceinline__ h2v pkrtz(float a, float b) {
#if __has_builtin(__builtin_amdgcn_cvt_pkrtz)
    return __builtin_bit_cast(h2v, __builtin_amdgcn_cvt_pkrtz(a, b));
#else
    return (h2v){(h16)a, (h16)b};
#endif
}

__device__ __forceinline__ float fexp2(float x) {
#if __has_builtin(__builtin_amdgcn_exp2f)
    return __builtin_amdgcn_exp2f(x);                // v_exp_f32
#else
    return exp2f(x);
#endif
}

__device__ __forceinline__ float frcp(float x) {
#if __has_builtin(__builtin_amdgcn_rcpf)
    return __builtin_amdgcn_rcpf(x);                 // v_rcp_f32
#else
    return 1.f / x;
#endif
}

// Quad-lane butterfly sum via DPP quad_perm (VALU pipe, no LDS traffic).
__device__ __forceinline__ float quad_sum(float x) {
#if __has_builtin(__builtin_amdgcn_mov_dpp)
    int i = __builtin_bit_cast(int, x);
    int a = __builtin_amdgcn_mov_dpp(i, 0xB1, 0xF, 0xF, true);  // quad xor 1
    float x1 = x + __builtin_bit_cast(float, a);
    int j = __builtin_bit_cast(int, x1);
    int b = __builtin_amdgcn_mov_dpp(j, 0x4E, 0xF, 0xF, true);  // quad xor 2
    return x1 + __builtin_bit_cast(float, b);
#else
    float x1 = x + __shfl_xor(x, 1);
    return x1 + __shfl_xor(x1, 2);
#endif
}

// ---- Kernel A: [B][C][H][W] f32 -> [B][H][W][C] f16 (channel-last) ----
#define TP_PAD 72       // h16 row stride: 144 B, 16B-aligned
__global__ __launch_bounds__(256) void rv_transpose(const float* __restrict__ x,
                                                    h16* __restrict__ xt) {
    __shared__ h16 buf[WW][TP_PAD];          // 18432 B
    const int t = threadIdx.x;
    const int h = blockIdx.x;
    const int b = blockIdx.y;
    const float* src = x + (size_t)b * (CCH * HWSZ) + h * WW;
#pragma unroll 4
    for (int i = 0; i < 16; ++i) {           // 32 ch-pairs x 128 w / 256 thr
        int k = i * 256 + t;
        int w  = k & 127;                    // lane-fast: coalesced loads
        int cp = k >> 7;                     // channel pair 0..31
        float v0 = src[(size_t)(2 * cp) * HWSZ + w];
        float v1 = src[(size_t)(2 * cp + 1) * HWSZ + w];
        *(h2v*)&buf[w][2 * cp] = pkrtz(v0, v1);  // one b32 write
    }
    __syncthreads();
    h16* dst = xt + (size_t)(b * HH + h) * WW * CCH;
#pragma unroll
    for (int j = 0; j < 4; ++j) {            // 128 px x 8 quads / 256 threads
        int idx = j * 256 + t;
        int w = idx >> 3;
        int q = idx & 7;                     // q fast: contiguous b128 stores
        h8v v = *(const h8v*)&buf[w][q * 8];
        *(h8v*)&dst[(size_t)w * CCH + q * 8] = v;
    }
}

// ---- Kernel B: fused one-pass (center logit == softmax max, exactly) ----
// Block: 256 threads = 4 waves. thread t -> pixel (t>>2), channel-quarter
// (t&3, 16 ch). sim <= 1 by Cauchy-Schwarz and center sim == 1, so each
// neighbor's weight is final on first visit (one LDS pass over the tile).
__global__ __launch_bounds__(256) void rv_fused(const h16* __restrict__ xt,
                                                float* __restrict__ out) {
    __shared__ h8v  tile[8][HPAD];   // 18560 B
    __shared__ float sh_rn[HPX];     // 576 B: per-halo-pixel 1/||x||

    const int t  = threadIdx.x;
    const int w0 = blockIdx.x * IT;
    const int h0 = blockIdx.y * IT;
    const int b  = blockIdx.z;

    // ---- Stage: 144 px x 8 quads. 8-lane group = one pixel's 128 B
    // contiguous global read; conflict-free b128 LDS write. ----
#pragma unroll
    for (int it = 0; it < 5; ++it) {
        int k = it * 256 + t;
        if (k < 8 * HPX) {
            int q  = k & 7;
            int px = k >> 3;             // 0..143
            int row = px / HT;
            int col = px - row * HT;
            int gh = h0 + row - 2;
            int gw = w0 + col - 2;
            h8v v = {};
            if ((unsigned)gh < (unsigned)HH && (unsigned)gw < (unsigned)WW) {
                v = *(const h8v*)&xt[((size_t)(b * HH + gh) * WW + gw) * CCH + q * 8];
            }
            tile[q][px] = v;
        }
    }
    __syncthreads();

    // ---- Per-halo-pixel reciprocal norm (from the SAME rounded f16) ----
    if (t < HPX) {
        float q = 0.f;
#pragma unroll
        for (int hq = 0; hq < 8; ++hq) {
            H8 u; u.v = tile[hq][t];
#pragma unroll
            for (int j = 0; j < 4; ++j) q = fdot2(u.p[j], u.p[j], q);
        }
        sh_rn[t] = rsqrtf(q + CEPS2);
    }
    __syncthreads();

    const int qg  = t & 3;               // channel quarter: planes 2qg, 2qg+1
    const int pix = t >> 2;              // 0..63
    const int r   = pix >> 3;
    const int cl  = pix & 7;
    const int cpx = (r + 2) * HT + (cl + 2);

    const float rinvC2 = K2E * sh_rn[cpx];   // fold TEMP/ln2 into center norm

    H8 ctr0, ctr1;
    ctr0.v = tile[2 * qg][cpx];
    ctr1.v = tile[2 * qg + 1][cpx];

    h2v acc[8] = {};                     // unnormalized numerator, 16 ch
    float wsum = 0.f;

#pragma unroll
    for (int dr = 0; dr < 5; ++dr) {
#pragma unroll
        for (int dc = 0; dc < 5; ++dc) {
            const int npx = (r + dr) * HT + (cl + dc);
            H8 a0, a1;
            a0.v = tile[2 * qg][npx];
            a1.v = tile[2 * qg + 1][npx];
            float d = 0.f;
#pragma unroll
            for (int j = 0; j < 4; ++j) d = fdot2(ctr0.p[j], a0.p[j], d);
#pragma unroll
            for (int j = 0; j < 4; ++j) d = fdot2(ctr1.p[j], a1.p[j], d);
            d = quad_sum(d);             // full 64-ch dot in all 4 quad lanes
            // wn = exp2(K2*sim - K2): 1 add, 2 mul/fma, 1 v_exp_f32
            const float u = (d + CEPS2) * sh_rn[npx];   // broadcast LDS read
            const float wn = fexp2(fmaf(u, rinvC2, -K2E));
            wsum += wn;
            const h16 wh = (h16)wn;
            const h2v w2 = {wh, wh};
#pragma unroll
            for (int j = 0; j < 4; ++j) {
                acc[j]     = a0.p[j] * w2 + acc[j];
                acc[4 + j] = a1.p[j] * w2 + acc[4 + j];
            }
        }
    }

    // ---- Normalize + store this quarter's 16 channels ----
    const float rs = frcp(wsum);         // wsum in [1,25]: approx rcp fine
    const size_t obase = (size_t)b * (CCH * HWSZ)
                       + (size_t)(qg * 16) * HWSZ
                       + (h0 + r) * WW + (w0 + cl);
#pragma unroll
    for (int j = 0; j < 8; ++j) {
        const float f0 = (float)acc[j][0];
        const float f1 = (float)acc[j][1];
        out[obase + (size_t)(2 * j) * HWSZ]     = fmaf(f0, rs, EPS);
        out[obase + (size_t)(2 * j + 1) * HWSZ] = fmaf(f1, rs, EPS);
    }
}

extern "C" void kernel_launch(void* const* d_in, const int* in_sizes, int n_in,
                              void* d_out, int out_size, void* d_ws, size_t ws_size,
                              hipStream_t stream) {
    const float* x = (const float*)d_in[0];
    float* outp = (float*)d_out;
    h16* xt = (h16*)d_ws;    // 4*128*128*64*2 B = 8.4 MB

    rv_transpose<<<dim3(HH, 4), dim3(256), 0, stream>>>(x, xt);
    rv_fused<<<dim3(WW / IT, HH / IT, 4), dim3(256, 1, 1), 0, stream>>>(xt, outp);
}